// Round 7
// baseline (543.725 us; speedup 1.0000x reference)
//
#include <hip/hip_runtime.h>

// B=2, L=S=2048, D_MODEL=1024, H=16, D_HEAD=64
// d_out = [out: 2*2048*1024 f32][A: 2*16*2048*2048 f32]

typedef __attribute__((ext_vector_type(8))) __bf16 bf16x8;
typedef __attribute__((ext_vector_type(4))) float f32x4;

__device__ __forceinline__ unsigned int f2bf_u(float f) {
  unsigned int u = __float_as_uint(f);
  return (u + 0x7FFFu + ((u >> 16) & 1u)) >> 16;  // RNE
}
__device__ __forceinline__ float bf2f(unsigned int h) {
  return __uint_as_float(h << 16);
}
__device__ __forceinline__ unsigned int pack2(float lo, float hi) {
  return (f2bf_u(hi) << 16) | f2bf_u(lo);
}
__device__ __forceinline__ f32x4 mfma16(bf16x8 a, bf16x8 b, f32x4 c) {
  return __builtin_amdgcn_mfma_f32_16x16x32_bf16(a, b, c, 0, 0, 0);
}
__device__ __forceinline__ void gll16(const void* g, void* l) {
  __builtin_amdgcn_global_load_lds(
      (const __attribute__((address_space(1))) unsigned int*)g,
      (__attribute__((address_space(3))) unsigned int*)l, 16, 0, 0);
}

// ---------------------------------------------------------------- transpose
// W[1024 in][1024 out] f32  ->  WT[1024 out][1024 in] bf16
__global__ __launch_bounds__(256) void transpose_w(
    const float* __restrict__ W0, const float* __restrict__ W1,
    const float* __restrict__ W2, const float* __restrict__ W3,
    unsigned short* __restrict__ T0, unsigned short* __restrict__ T1,
    unsigned short* __restrict__ T2, unsigned short* __restrict__ T3) {
  const float* W; unsigned short* T;
  switch (blockIdx.z) {
    case 0: W = W0; T = T0; break;
    case 1: W = W1; T = T1; break;
    case 2: W = W2; T = T2; break;
    default: W = W3; T = T3; break;
  }
  __shared__ float tile[32][33];
  const int tx = threadIdx.x, ty = threadIdx.y;  // 32 x 8
  const int i0 = blockIdx.x * 32, o0 = blockIdx.y * 32;
  #pragma unroll
  for (int r = 0; r < 4; ++r)
    tile[ty + 8 * r][tx] = W[(size_t)(i0 + ty + 8 * r) * 1024 + o0 + tx];
  __syncthreads();
  #pragma unroll
  for (int r = 0; r < 4; ++r)
    T[(size_t)(o0 + ty + 8 * r) * 1024 + i0 + tx] =
        (unsigned short)f2bf_u(tile[tx][ty + 8 * r]);
}

// ---------------------------------------------------------------- GEMM 128x128
// C[M,N] = A[M,K]*BT[N,K]^T + bias
// OMODE: 0 = bf16 row-major C, 1 = f32 row-major C, 2 = bf16 transposed VT[bh][d][s]
template <bool A_BF16, int OMODE>
__global__ __launch_bounds__(256) void gemm128(
    const void* __restrict__ Ap, const unsigned short* __restrict__ BT,
    const float* __restrict__ bias, void* __restrict__ Cp,
    int M, int N, int K) {
  constexpr int AS = A_BF16 ? 32 : 40;  // pad f32-staged tile to dodge conflicts
  __shared__ unsigned short As[128][AS];
  __shared__ unsigned short Bs[128][32];
  const int tid = threadIdx.x;
  const int lane = tid & 63, wid = tid >> 6;
  const int l15 = lane & 15, l4 = lane >> 4;
  const int m0 = blockIdx.x * 128, n0 = blockIdx.y * 128;
  const int wr = wid >> 1, wc = wid & 1;

  f32x4 acc[4][4];
  #pragma unroll
  for (int i = 0; i < 4; ++i)
    #pragma unroll
    for (int j = 0; j < 4; ++j) acc[i][j] = (f32x4){0.f, 0.f, 0.f, 0.f};

  const int nk = K >> 5;
  for (int kt = 0; kt < nk; ++kt) {
    if constexpr (A_BF16) {
      const unsigned short* G = (wid < 2)
          ? ((const unsigned short*)Ap + (size_t)m0 * K)
          : (BT + (size_t)n0 * K);
      char* L = (wid < 2) ? (char*)&As[0][0] : (char*)&Bs[0][0];
      const int half = wid & 1;
      #pragma unroll
      for (int c = 0; c < 4; ++c) {
        const int off = half * 4096 + c * 1024;
        const int loff = off + lane * 16;
        const int row = loff >> 6, colb = loff & 63;
        gll16(G + (size_t)row * K + kt * 32 + colb / 2, L + off);
      }
    } else {
      if (wid < 2) {  // A f32 -> bf16, chunk-coalesced (8 rows x 128B per instr)
        #pragma unroll
        for (int c = 0; c < 8; ++c) {
          const int chunk = c * 128 + tid;
          const int row = chunk >> 3, col4 = chunk & 7;
          const float4 f = *(const float4*)((const float*)Ap +
                                            (size_t)(m0 + row) * K + kt * 32 + col4 * 4);
          ushort4 o;
          o.x = (unsigned short)f2bf_u(f.x);
          o.y = (unsigned short)f2bf_u(f.y);
          o.z = (unsigned short)f2bf_u(f.z);
          o.w = (unsigned short)f2bf_u(f.w);
          *(ushort4*)&As[row][col4 * 4] = o;
        }
      } else {
        const int half = wid & 1;
        #pragma unroll
        for (int c = 0; c < 4; ++c) {
          const int off = half * 4096 + c * 1024;
          const int loff = off + lane * 16;
          const int row = loff >> 6, colb = loff & 63;
          gll16(BT + (size_t)(n0 + row) * K + kt * 32 + colb / 2,
                (char*)&Bs[0][0] + off);
        }
      }
    }
    __syncthreads();
    bf16x8 af[4], bfr[4];
    #pragma unroll
    for (int i = 0; i < 4; ++i)
      af[i] = *(const bf16x8*)&As[wr * 64 + i * 16 + l15][l4 * 8];
    #pragma unroll
    for (int j = 0; j < 4; ++j)
      bfr[j] = *(const bf16x8*)&Bs[wc * 64 + j * 16 + l15][l4 * 8];
    #pragma unroll
    for (int i = 0; i < 4; ++i)
      #pragma unroll
      for (int j = 0; j < 4; ++j)
        acc[i][j] = mfma16(af[i], bfr[j], acc[i][j]);
    __syncthreads();
  }

  #pragma unroll
  for (int j = 0; j < 4; ++j) {
    const int col = n0 + wc * 64 + j * 16 + l15;
    const float bv = bias[col];
    #pragma unroll
    for (int i = 0; i < 4; ++i) {
      const int rowb = m0 + wr * 64 + i * 16 + l4 * 4;
      if constexpr (OMODE == 2) {
        const int bq = rowb >> 11, sq = rowb & 2047;
        const int hq = col >> 6, dq = col & 63;
        ushort4 o;
        o.x = (unsigned short)f2bf_u(acc[i][j][0] + bv);
        o.y = (unsigned short)f2bf_u(acc[i][j][1] + bv);
        o.z = (unsigned short)f2bf_u(acc[i][j][2] + bv);
        o.w = (unsigned short)f2bf_u(acc[i][j][3] + bv);
        *(ushort4*)((unsigned short*)Cp +
                    ((size_t)((bq * 16 + hq) * 64 + dq) << 11) + sq) = o;
      } else {
        #pragma unroll
        for (int q = 0; q < 4; ++q) {
          const float v = acc[i][j][q] + bv;
          if constexpr (OMODE == 1)
            ((float*)Cp)[(size_t)(rowb + q) * N + col] = v;
          else
            ((unsigned short*)Cp)[(size_t)(rowb + q) * N + col] =
                (unsigned short)f2bf_u(v);
        }
      }
    }
  }
}

// ---------------------------------------------------------------- fused attention
// grid (L/16=128, B*H=32), block 512 (8 waves). 16 q-rows/WG, s split 8 ways.
// R4-proven dataflow (stored bf16 scores, max-sub, e-based PV, end 1/l scale),
// re-partitioned over 8 waves: sc[32]/lane (was 64) -> lower VGPR, 3x occupancy.
// Phase1: i = 128-block index; lane scores s = i*128 + w*16 + l4*4 + j, q-row=l15.
// Phase2: u pairs blocks (2u,2u+1); A-frag k=l4*8+j: j<4 -> blk 2u, j>=4 -> 2u+1;
// V B-frag: two uint2 loads at +0 / +128 from VT[bh][d][s].
__global__ __launch_bounds__(512) void attn_fused(
    const unsigned short* __restrict__ Q, const unsigned short* __restrict__ K,
    const unsigned short* __restrict__ VT, float* __restrict__ Aout,
    unsigned short* __restrict__ OutPre) {
  __shared__ float stats[8][16];
  __shared__ float mrow[16];
  __shared__ float lrow[16];
  __shared__ float red[8][16][68];

  const int tid = threadIdx.x;
  const int w = tid >> 6, lane = tid & 63;
  const int l15 = lane & 15, l4 = lane >> 4;
  const int bh = blockIdx.y, b = bh >> 4, h = bh & 15;
  const int m0 = blockIdx.x * 16;

  // Q fragment (B-operand: lane l15 = q-row m, k-chunk = l4*8)
  const unsigned short* Qp =
      Q + ((size_t)(b * 2048 + m0 + l15) << 10) + h * 64 + l4 * 8;
  const bf16x8 qf0 = *(const bf16x8*)Qp;
  const bf16x8 qf1 = *(const bf16x8*)(Qp + 32);

  const unsigned short* Kb = K + ((size_t)b << 21) + h * 64;
  unsigned int sc[32];  // packed bf16 scaled scores
  float rmax = -3.0e38f;

  // ---- phase 1: scores^T = K·Q^T, keep in registers, track max
  #pragma unroll
  for (int i = 0; i < 16; ++i) {
    const unsigned short* kp =
        Kb + ((size_t)(i * 128 + w * 16 + l15) << 10) + l4 * 8;
    const bf16x8 k0 = *(const bf16x8*)kp;
    const bf16x8 k1 = *(const bf16x8*)(kp + 32);
    f32x4 a = {0.f, 0.f, 0.f, 0.f};
    a = mfma16(k0, qf0, a);
    a = mfma16(k1, qf1, a);
    const float s0 = a[0] * 0.125f, s1 = a[1] * 0.125f;
    const float s2 = a[2] * 0.125f, s3 = a[3] * 0.125f;
    rmax = fmaxf(rmax, fmaxf(fmaxf(s0, s1), fmaxf(s2, s3)));
    sc[i * 2 + 0] = pack2(s0, s1);
    sc[i * 2 + 1] = pack2(s2, s3);
  }
  rmax = fmaxf(rmax, __shfl_xor(rmax, 16));
  rmax = fmaxf(rmax, __shfl_xor(rmax, 32));
  if (lane < 16) stats[w][l15] = rmax;
  __syncthreads();
  if (tid < 16) {
    float m = stats[0][tid];
    #pragma unroll
    for (int ww = 1; ww < 8; ++ww) m = fmaxf(m, stats[ww][tid]);
    mrow[tid] = m;
  }
  __syncthreads();
  const float mreg = mrow[l15];

  float lsum = 0.f;
  #pragma unroll
  for (int r = 0; r < 32; ++r) {
    const unsigned int p = sc[r];
    lsum += __expf(bf2f(p & 0xffffu) - mreg) + __expf(bf2f(p >> 16) - mreg);
  }
  lsum += __shfl_xor(lsum, 16);
  lsum += __shfl_xor(lsum, 32);
  if (lane < 16) stats[w][l15] = lsum;
  __syncthreads();
  if (tid < 16) {
    float s = 0.f;
    #pragma unroll
    for (int ww = 0; ww < 8; ++ww) s += stats[ww][tid];
    lrow[tid] = 1.0f / s;
  }
  __syncthreads();
  const float lreg = lrow[l15];

  // ---- phase 2: A-write + PV, no barriers, no shuffles
  const unsigned short* Vb = VT + ((size_t)bh << 17);  // [64 d][2048 s]
  float* Ab = Aout + ((size_t)bh << 22) + ((size_t)(m0 + l15) << 11) + w * 16 + l4 * 4;
  f32x4 pv[4];
  #pragma unroll
  for (int nt = 0; nt < 4; ++nt) pv[nt] = (f32x4){0.f, 0.f, 0.f, 0.f};

  #pragma unroll
  for (int u = 0; u < 8; ++u) {
    unsigned int epA[2], epB[2];
    {  // s-block 2u
      const unsigned int p0 = sc[4 * u + 0], p1 = sc[4 * u + 1];
      const float e0 = __expf(bf2f(p0 & 0xffffu) - mreg);
      const float e1 = __expf(bf2f(p0 >> 16) - mreg);
      const float e2 = __expf(bf2f(p1 & 0xffffu) - mreg);
      const float e3 = __expf(bf2f(p1 >> 16) - mreg);
      const f32x4 av = {e0 * lreg, e1 * lreg, e2 * lreg, e3 * lreg};
      __builtin_nontemporal_store(av, (f32x4*)(Ab + u * 256));
      epA[0] = pack2(e0, e1);
      epA[1] = pack2(e2, e3);
    }
    {  // s-block 2u+1
      const unsigned int p0 = sc[4 * u + 2], p1 = sc[4 * u + 3];
      const float e0 = __expf(bf2f(p0 & 0xffffu) - mreg);
      const float e1 = __expf(bf2f(p0 >> 16) - mreg);
      const float e2 = __expf(bf2f(p1 & 0xffffu) - mreg);
      const float e3 = __expf(bf2f(p1 >> 16) - mreg);
      const f32x4 av = {e0 * lreg, e1 * lreg, e2 * lreg, e3 * lreg};
      __builtin_nontemporal_store(av, (f32x4*)(Ab + u * 256 + 128));
      epB[0] = pack2(e0, e1);
      epB[1] = pack2(e2, e3);
    }
    // A-operand fragment: lane-local (k = l4*8+j ; j<4 -> block 2u, j>=4 -> 2u+1)
    union { unsigned int u4[4]; bf16x8 v; } ef;
    ef.u4[0] = epA[0]; ef.u4[1] = epA[1];
    ef.u4[2] = epB[0]; ef.u4[3] = epB[1];
    const unsigned short* vtp = Vb + (size_t)l15 * 2048 + u * 256 + w * 16 + l4 * 4;
    #pragma unroll
    for (int nt = 0; nt < 4; ++nt) {
      const unsigned short* pp = vtp + (size_t)(nt * 16) * 2048;
      union { unsigned int u4[4]; bf16x8 v; } vf;
      const uint2 va = *(const uint2*)pp;          // block 2u   : offs l4*4+0..3
      const uint2 vb = *(const uint2*)(pp + 128);  // block 2u+1 : offs l4*4+0..3
      vf.u4[0] = va.x; vf.u4[1] = va.y; vf.u4[2] = vb.x; vf.u4[3] = vb.y;
      pv[nt] = mfma16(ef.v, vf.v, pv[nt]);
    }
  }

  // ---- cross-wave PV reduce (once), scale by 1/l, write out_pre
  #pragma unroll
  for (int nt = 0; nt < 4; ++nt)
    #pragma unroll
    for (int q = 0; q < 4; ++q)
      red[w][l4 * 4 + q][nt * 16 + l15] = pv[nt][q];
  __syncthreads();
  {
    const int m = tid >> 5, d2 = (tid & 31) * 2;
    float s0 = 0.f, s1 = 0.f;
    #pragma unroll
    for (int ww = 0; ww < 8; ++ww) {
      s0 += red[ww][m][d2];
      s1 += red[ww][m][d2 + 1];
    }
    const float li = lrow[m];
    ushort2 o;
    o.x = (unsigned short)f2bf_u(s0 * li);
    o.y = (unsigned short)f2bf_u(s1 * li);
    *(ushort2*)(OutPre + ((size_t)(b * 2048 + m0 + m) << 10) + h * 64 + d2) = o;
  }
}

// ---------------------------------------------------------------- launcher
extern "C" void kernel_launch(void* const* d_in, const int* in_sizes, int n_in,
                              void* d_out, int out_size, void* d_ws,
                              size_t ws_size, hipStream_t stream) {
  (void)in_sizes; (void)n_in; (void)out_size; (void)ws_size;
  const float* queries = (const float*)d_in[0];
  const float* keys    = (const float*)d_in[1];
  const float* values  = (const float*)d_in[2];
  const float* Wq = (const float*)d_in[3];  const float* bq = (const float*)d_in[4];
  const float* Wk = (const float*)d_in[5];  const float* bk = (const float*)d_in[6];
  const float* Wv = (const float*)d_in[7];  const float* bv = (const float*)d_in[8];
  const float* Wo = (const float*)d_in[9];  const float* bo = (const float*)d_in[10];

  float* out  = (float*)d_out;
  float* Aout = out + (size_t)2 * 2048 * 1024;

  char* ws = (char*)d_ws;
  unsigned short* WqT = (unsigned short*)(ws + 0);
  unsigned short* WkT = (unsigned short*)(ws + 2097152);
  unsigned short* WvT = (unsigned short*)(ws + 4194304);
  unsigned short* WoT = (unsigned short*)(ws + 6291456);
  unsigned short* Qb  = (unsigned short*)(ws + 8388608);
  unsigned short* Kbf = (unsigned short*)(ws + 16777216);
  unsigned short* VTb = (unsigned short*)(ws + 25165824);  // [bh][64][2048]
  unsigned short* Op  = (unsigned short*)(ws + 33554432);  // out_pre bf16

  transpose_w<<<dim3(32, 32, 4), dim3(32, 8), 0, stream>>>(
      Wq, Wk, Wv, Wo, WqT, WkT, WvT, WoT);

  gemm128<false, 0><<<dim3(32, 8), 256, 0, stream>>>(
      queries, WqT, bq, Qb, 4096, 1024, 1024);
  gemm128<false, 0><<<dim3(32, 8), 256, 0, stream>>>(
      keys, WkT, bk, Kbf, 4096, 1024, 1024);
  gemm128<false, 2><<<dim3(32, 8), 256, 0, stream>>>(
      values, WvT, bv, VTb, 4096, 1024, 1024);

  attn_fused<<<dim3(128, 32), 512, 0, stream>>>(Qb, Kbf, VTb, Aout, Op);

  gemm128<true, 1><<<dim3(32, 8), 256, 0, stream>>>(
      Op, WoT, bo, out, 4096, 1024, 1024);
}